// Round 5
// baseline (328.657 us; speedup 1.0000x reference)
//
#include <hip/hip_runtime.h>
#include <hip/hip_fp16.h>
#include <math.h>

// Problem constants (fixed by reference setup_inputs)
#define N_NODES 100000
#define N_INCID 2000000
#define HIDDEN  128
#define N_HE    100000

#define EPB 1024                                   // edges per fill block (ILP-4)
#define FILL_BLOCKS ((N_INCID + EPB - 1) / EPB)    // 1954
#define PREP_BLOCKS ((N_NODES + 3) / 4)            // 25000

#define SLOTS 4                                    // concurrent chain streams per half-wave
#define HE_PER_HW 8                                // hyperedges per half-wave (2 per slot)
#define N_HW (N_HE / HE_PER_HW)                    // 12500 half-waves (divides exactly)
#define COMP_BLOCKS ((N_HW + 7) / 8)               // 1563 blocks (8 half-waves each)

typedef float vf4 __attribute__((ext_vector_type(4)));  // native vec for nontemporal st

__device__ inline float4 h4_to_f4(uint2 p) {
    __half2 a = *(__half2*)&p.x;
    __half2 b = *(__half2*)&p.y;
    float2 fa = __half22float2(a);
    float2 fb = __half22float2(b);
    return make_float4(fa.x, fa.y, fb.x, fb.y);
}

// K1 (fused, R0-proven structure, CHAINS=1):
//  - fill blocks: linked-list CSR build. prev = atomicExch(head[he], e) on a
//    400 KB L2-resident array; next8[e] = {nd, prev} is a COALESCED 8 B store
//    (R6 lesson: scattered 4 B stores into big arrays cost 146 MB write-amp).
//  - prep blocks: en[n] = exp(dot(f[n],W)) + fp16 copy of feats (BW-bound).
__global__ void prep_fill_kernel(const float* __restrict__ nf,
                                 const float* __restrict__ W,
                                 const int* __restrict__ idx,
                                 float* __restrict__ en,
                                 __half2* __restrict__ nfh2,
                                 int* __restrict__ head,
                                 int2* __restrict__ next8) {
    int b = blockIdx.x;
    if (b < FILL_BLOCKS) {
        int base = b * EPB;
        int e = base + threadIdx.x;
        if (base + EPB <= N_INCID) {
            int he[4], nd[4], prev[4];
            #pragma unroll
            for (int k = 0; k < 4; ++k) {
                he[k] = idx[N_INCID + e + 256 * k];
                nd[k] = idx[e + 256 * k];
            }
            #pragma unroll
            for (int k = 0; k < 4; ++k)
                prev[k] = atomicExch(&head[he[k]], e + 256 * k);
            #pragma unroll
            for (int k = 0; k < 4; ++k)
                next8[e + 256 * k] = make_int2(nd[k], prev[k]);
        } else {
            #pragma unroll
            for (int k = 0; k < 4; ++k) {
                int ek = e + 256 * k;
                if (ek < N_INCID) {
                    int he = idx[N_INCID + ek];
                    int nd = idx[ek];
                    int prev = atomicExch(&head[he], ek);
                    next8[ek] = make_int2(nd, prev);
                }
            }
        }
    } else {
        int wave = threadIdx.x >> 6, lane = threadIdx.x & 63;
        int n = (b - FILL_BLOCKS) * 4 + wave;
        if (n >= N_NODES) return;
        const float2* nf2 = (const float2*)nf;
        const float2* w2  = (const float2*)W;
        float2 v = nf2[(size_t)n * 64 + lane];
        float2 w = w2[lane];
        float p = v.x * w.x + v.y * w.y;
        #pragma unroll
        for (int o = 32; o > 0; o >>= 1) p += __shfl_xor(p, o, 64);
        if (lane == 0) en[n] = __expf(p);
        nfh2[(size_t)n * 64 + lane] = __floats2half2_rn(v.x, v.y);
    }
}

// K2 (slot-refill): each half-wave owns 8 consecutive hyperedges, walked by
// 4 SLOTS. Each slot serially walks one he's chain; when the chain ends the
// slot finalizes (normalize + store) and refills with its next he. Sustained
// MLP ~3.4 with ~zero wasted hop-slots — R4's lesson was that clamped waste
// slots throttle useful BW; R3's lesson was that clean MLP=2 gains +15% BW.
// e[s] semantics: >=0 live edge, -1 chain just ended (finalize), -2 slot idle.
__global__ void compute_kernel_s(const int* __restrict__ head,
                                 const int2* __restrict__ next8,
                                 const float* __restrict__ en,
                                 const uint2* __restrict__ nfh4,
                                 float* __restrict__ out) {
    int wave = threadIdx.x >> 6, lane = threadIdx.x & 63;
    int half = lane >> 5, l32 = lane & 31;
    int hw = blockIdx.x * 8 + wave * 2 + half;     // half-wave id
    if (hw >= N_HW) return;
    int base = hw * HE_PER_HW;

    const long long* __restrict__ nxt = (const long long*)next8;

    int heq[SLOTS], e[SLOTS];
    float4 acc[SLOTS];
    float den[SLOTS];
    #pragma unroll
    for (int s = 0; s < SLOTS; ++s) {
        heq[s] = base + s;                 // slot stream: base+s, base+s+4
        e[s]   = head[heq[s]];
        acc[s] = make_float4(0.f, 0.f, 0.f, 0.f);
        den[s] = 0.f;
    }

    while (true) {
        // finalize/refill: convert every -1 to a fresh chain (or -2 idle)
        if ((e[0] == -1) || (e[1] == -1) || (e[2] == -1) || (e[3] == -1)) {
            #pragma unroll
            for (int s = 0; s < SLOTS; ++s) {
                while (e[s] == -1) {
                    float inv = 1.0f / fmaxf(den[s], 1e-20f);
                    vf4 o = { acc[s].x * inv, acc[s].y * inv,
                              acc[s].z * inv, acc[s].w * inv };
                    __builtin_nontemporal_store(
                        o, (vf4*)&((float4*)out)[(size_t)heq[s] * 32 + l32]);
                    acc[s] = make_float4(0.f, 0.f, 0.f, 0.f);
                    den[s] = 0.f;
                    heq[s] += SLOTS;
                    e[s] = (heq[s] < base + HE_PER_HW) ? head[heq[s]] : -2;
                }
            }
            if ((e[0] & e[1] & e[2] & e[3]) == -2) break;   // all idle
        }

        // hop phase: 4 independent {next, en, row} load groups in flight.
        // Idle slots (-2, tail only ~13% of slot-rounds) read entry 0 (L1-hot).
        long long q0 = nxt[e[0] >= 0 ? e[0] : 0];
        long long q1 = nxt[e[1] >= 0 ? e[1] : 0];
        long long q2 = nxt[e[2] >= 0 ? e[2] : 0];
        long long q3 = nxt[e[3] >= 0 ? e[3] : 0];

        int n0 = (int)q0, n1 = (int)q1, n2 = (int)q2, n3 = (int)q3;

        float w0 = en[n0]; w0 = (e[0] >= 0) ? w0 : 0.f;
        float w1 = en[n1]; w1 = (e[1] >= 0) ? w1 : 0.f;
        float w2 = en[n2]; w2 = (e[2] >= 0) ? w2 : 0.f;
        float w3 = en[n3]; w3 = (e[3] >= 0) ? w3 : 0.f;

        float4 v0 = h4_to_f4(nfh4[(size_t)n0 * 32 + l32]);
        float4 v1 = h4_to_f4(nfh4[(size_t)n1 * 32 + l32]);
        float4 v2 = h4_to_f4(nfh4[(size_t)n2 * 32 + l32]);
        float4 v3 = h4_to_f4(nfh4[(size_t)n3 * 32 + l32]);

        acc[0].x += w0 * v0.x; acc[0].y += w0 * v0.y;
        acc[0].z += w0 * v0.z; acc[0].w += w0 * v0.w; den[0] += w0;
        acc[1].x += w1 * v1.x; acc[1].y += w1 * v1.y;
        acc[1].z += w1 * v1.z; acc[1].w += w1 * v1.w; den[1] += w1;
        acc[2].x += w2 * v2.x; acc[2].y += w2 * v2.y;
        acc[2].z += w2 * v2.z; acc[2].w += w2 * v2.w; den[2] += w2;
        acc[3].x += w3 * v3.x; acc[3].y += w3 * v3.y;
        acc[3].z += w3 * v3.z; acc[3].w += w3 * v3.w; den[3] += w3;

        e[0] = (e[0] >= 0) ? (int)(q0 >> 32) : -2;
        e[1] = (e[1] >= 0) ? (int)(q1 >> 32) : -2;
        e[2] = (e[2] >= 0) ? (int)(q2 >> 32) : -2;
        e[3] = (e[3] >= 0) ? (int)(q3 >> 32) : -2;
    }
}

extern "C" void kernel_launch(void* const* d_in, const int* in_sizes, int n_in,
                              void* d_out, int out_size, void* d_ws, size_t ws_size,
                              hipStream_t stream) {
    const float* nf  = (const float*)d_in[0];
    const int*   idx = (const int*)d_in[1];   // int32: harness downcasts int64
    const float* W   = (const float*)d_in[3];
    float* out = (float*)d_out;
    char* ws = (char*)d_ws;

    int*     head  = (int*)(ws + 0);            // 400 KB  (1 chain x 100K)
    float*   en    = (float*)(ws + 400000);     // 400 KB
    __half2* nfh2  = (__half2*)(ws + 800000);   // 25.6 MB
    int2*    next8 = (int2*)(ws + 26400000);    // 16 MB   (total 42.4 MB < proven 52 MB)

    hipMemsetAsync(head, 0xFF, N_HE * sizeof(int), stream);   // head[he] = -1
    prep_fill_kernel<<<FILL_BLOCKS + PREP_BLOCKS, 256, 0, stream>>>(
        nf, W, idx, en, nfh2, head, next8);
    compute_kernel_s<<<COMP_BLOCKS, 256, 0, stream>>>(
        head, next8, en, (const uint2*)nfh2, out);
}